// Round 13
// baseline (769.209 us; speedup 1.0000x reference)
//
#include <hip/hip_runtime.h>

// GCNConv: out = D^-1/2 (A + I) D^-1/2 (x W) + b
// x: [N,256] f32, edge_index: [2,E] int, W: [256,64] f32, b: [64] f32
// out: [N,64] f32
//
// Pipeline: init (wfrag + 391-bin hist) -> bin_scan -> mega (MFMA GEMM h=xW
// overlapped with coarse scatter into bin-sorted ebuf) -> fine_deg (dinv) ->
// aggregate (per-bin LDS f32 accumulator, direct out write). No per-node CSR.

#define IN_F 256
#define OUT_F 64
#define WBITS 8                  // fine window = 256 nodes per bin
#define MAXBINS 512
#define ROWMASK 0xFFFFFFu        // n < 2^24
#define SCAT_BLOCKS 512

typedef unsigned short ushort_t;
typedef short bf16x8 __attribute__((ext_vector_type(8)));
typedef float f32x4 __attribute__((ext_vector_type(4)));

static __device__ __forceinline__ unsigned f2bf1(float f) {
    unsigned u = __float_as_uint(f);
    return (u + 0x7FFFu + ((u >> 16) & 1u)) >> 16;   // RNE
}
static __device__ __forceinline__ unsigned pk2(float a, float b) {
    return f2bf1(a) | (f2bf1(b) << 16);
}
static __device__ __forceinline__ ushort_t f2bf(float f) { return (ushort_t)f2bf1(f); }
static __device__ __forceinline__ float bf2f(ushort_t h) {
    return __uint_as_float(((unsigned)h) << 16);
}

// --- K1: wfrag pack (first 2048 threads) + coarse bin histogram (all blocks) ---
__global__ __launch_bounds__(256) void init_kernel(const float* __restrict__ W,
                                                   ushort_t* __restrict__ wfrag,
                                                   const int* __restrict__ col,
                                                   int* __restrict__ binCnt,
                                                   int E, int nbins) {
    int gt = blockIdx.x * 256 + threadIdx.x;
    if (gt < 2048) {   // W fragment pack: slot t=(kk*4+ct)*64+l
        int t = gt;
        int kk = t >> 8;
        int ct = (t >> 6) & 3;
        int l  = t & 63;
        int k0 = kk * 32 + (l >> 4) * 8;
        int c  = ct * 16 + (l & 15);
        unsigned u0 = pk2(W[(k0 + 0) * OUT_F + c], W[(k0 + 1) * OUT_F + c]);
        unsigned u1 = pk2(W[(k0 + 2) * OUT_F + c], W[(k0 + 3) * OUT_F + c]);
        unsigned u2 = pk2(W[(k0 + 4) * OUT_F + c], W[(k0 + 5) * OUT_F + c]);
        unsigned u3 = pk2(W[(k0 + 6) * OUT_F + c], W[(k0 + 7) * OUT_F + c]);
        ((uint4*)wfrag)[t] = make_uint4(u0, u1, u2, u3);
    }
    __shared__ int hist[MAXBINS];
    int tid = threadIdx.x;
    for (int i = tid; i < nbins; i += 256) hist[i] = 0;
    __syncthreads();
    int stride = gridDim.x * 256;
    for (int e = blockIdx.x * 256 + tid; e < E; e += stride)
        atomicAdd(&hist[col[e] >> WBITS], 1);
    __syncthreads();
    for (int i = tid; i < nbins; i += 256)
        if (hist[i]) atomicAdd(&binCnt[i], hist[i]);
}

// --- K2: exclusive scan of binCnt -> binStart, binCursor ---
__global__ void bin_scan_kernel(const int* __restrict__ binCnt, int* __restrict__ binStart,
                                int* __restrict__ binCursor, int nbins) {
    __shared__ int lds[512];
    int tid = threadIdx.x;   // 512 threads
    int v = (tid < nbins) ? binCnt[tid] : 0;
    lds[tid] = v;
    __syncthreads();
    for (int d = 1; d < 512; d <<= 1) {
        int t = (tid >= d) ? lds[tid - d] : 0;
        __syncthreads();
        lds[tid] += t;
        __syncthreads();
    }
    if (tid < nbins) {
        int ex = lds[tid] - v;
        binStart[tid] = ex;
        binCursor[tid] = ex;
    }
    if (tid == 511) binStart[nbins] = lds[511];   // = E
}

// --- K3 MEGA: blocks [0,gemmBlocks) = MFMA GEMM h=xW (bf16, unscaled);
//              blocks [gemmBlocks, +SCAT_BLOCKS) = coarse scatter ---
__global__ __launch_bounds__(256) void mega_kernel(const float* __restrict__ x,
                                                   const ushort_t* __restrict__ wfrag,
                                                   ushort_t* __restrict__ h,
                                                   const int* __restrict__ row,
                                                   const int* __restrict__ col,
                                                   int* __restrict__ binCursor,
                                                   unsigned* __restrict__ ebuf,
                                                   int n, int E, int nbins, int gemmBlocks) {
    __shared__ int cnt[MAXBINS];
    __shared__ int cur[MAXBINS];
    int tid = threadIdx.x;

    if (blockIdx.x < gemmBlocks) {
        // ---------------- GEMM path ----------------
        int l  = tid & 63;
        int lr = l & 15;
        int lg = l >> 4;
        int rowbase = blockIdx.x * 64 + (tid >> 6) * 16;
        int arow = rowbase + lr;
        int lrow = (arow < n) ? arow : (n - 1);
        const float* xp = x + (size_t)lrow * IN_F + lg * 8;
        const uint4* wf = (const uint4*)wfrag;

        f32x4 acc0 = {0.f, 0.f, 0.f, 0.f};
        f32x4 acc1 = {0.f, 0.f, 0.f, 0.f};
        f32x4 acc2 = {0.f, 0.f, 0.f, 0.f};
        f32x4 acc3 = {0.f, 0.f, 0.f, 0.f};

        #pragma unroll
        for (int kk = 0; kk < 8; ++kk) {
            float4 xa = *(const float4*)(xp + kk * 32);
            float4 xb = *(const float4*)(xp + kk * 32 + 4);
            union { bf16x8 v; unsigned u[4]; } A;
            A.u[0] = pk2(xa.x, xa.y);
            A.u[1] = pk2(xa.z, xa.w);
            A.u[2] = pk2(xb.x, xb.y);
            A.u[3] = pk2(xb.z, xb.w);
            union { uint4 q; bf16x8 v; } B0, B1, B2, B3;
            B0.q = wf[(kk * 4 + 0) * 64 + l];
            B1.q = wf[(kk * 4 + 1) * 64 + l];
            B2.q = wf[(kk * 4 + 2) * 64 + l];
            B3.q = wf[(kk * 4 + 3) * 64 + l];
            acc0 = __builtin_amdgcn_mfma_f32_16x16x32_bf16(A.v, B0.v, acc0, 0, 0, 0);
            acc1 = __builtin_amdgcn_mfma_f32_16x16x32_bf16(A.v, B1.v, acc1, 0, 0, 0);
            acc2 = __builtin_amdgcn_mfma_f32_16x16x32_bf16(A.v, B2.v, acc2, 0, 0, 0);
            acc3 = __builtin_amdgcn_mfma_f32_16x16x32_bf16(A.v, B3.v, acc3, 0, 0, 0);
        }

        #pragma unroll
        for (int q = 0; q < 4; ++q) {
            int r = rowbase + lg * 4 + q;
            if (r < n) {
                ushort_t* gp = h + (size_t)r * OUT_F + lr;
                gp[0]  = f2bf(acc0[q]);
                gp[16] = f2bf(acc1[q]);
                gp[32] = f2bf(acc2[q]);
                gp[48] = f2bf(acc3[q]);
            }
        }
    } else {
        // ---------------- coarse scatter path ----------------
        int sb = blockIdx.x - gemmBlocks;   // 0..SCAT_BLOCKS-1
        for (int i = tid; i < nbins; i += 256) cnt[i] = 0;
        __syncthreads();
        int chunk = (E + SCAT_BLOCKS - 1) / SCAT_BLOCKS;
        int s = sb * chunk;
        int epos = min(E, s + chunk);
        for (int e = s + tid; e < epos; e += 256)
            atomicAdd(&cnt[col[e] >> WBITS], 1);
        __syncthreads();
        for (int i = tid; i < nbins; i += 256) {
            int c = cnt[i];
            cur[i] = c ? atomicAdd(&binCursor[i], c) : 0;
        }
        __syncthreads();
        for (int e = s + tid; e < epos; e += 256) {
            int cc = col[e];
            int pos = atomicAdd(&cur[cc >> WBITS], 1);
            ebuf[pos] = (unsigned)row[e] | ((unsigned)(cc & ((1 << WBITS) - 1)) << 24);
        }
    }
}

// --- K4: per-bin deg histogram -> dinv ---
__global__ __launch_bounds__(256) void fine_deg_kernel(const unsigned* __restrict__ ebuf,
                                                       const int* __restrict__ binStart,
                                                       float* __restrict__ dinv, int n) {
    __shared__ int sdeg[256];
    int bin = blockIdx.x;
    int lo = bin << WBITS;
    int tid = threadIdx.x;
    sdeg[tid] = 0;
    __syncthreads();
    int s = binStart[bin], e1 = binStart[bin + 1];
    for (int e = s + tid; e < e1; e += 256)
        atomicAdd(&sdeg[ebuf[e] >> 24], 1);
    __syncthreads();
    if (lo + tid < n) dinv[lo + tid] = rsqrtf((float)(sdeg[tid] + 1));
}

// --- K5: per-bin aggregate into LDS f32 accum, write out directly ---
// accum layout (k-major swizzle): feature f of node c at float-offset
// c*64 + (f%4)*16 + f/4  -> each ds_add wave-op spreads over 16 banks (4-way).
__global__ __launch_bounds__(256) void aggregate_kernel(const unsigned* __restrict__ ebuf,
                                                        const int* __restrict__ binStart,
                                                        const ushort_t* __restrict__ h,
                                                        const float* __restrict__ dinv,
                                                        const float* __restrict__ b,
                                                        float* __restrict__ out, int n) {
    __shared__ float accum[256 * OUT_F];   // 64 KB
    int bin = blockIdx.x;
    int lo  = bin << WBITS;
    int wcnt = min(256, n - lo);
    int tid = threadIdx.x;

    float4* az = (float4*)accum;
    for (int i = tid; i < 256 * OUT_F / 4; i += 256) az[i] = make_float4(0.f, 0.f, 0.f, 0.f);
    __syncthreads();

    int lane = tid & 63;
    int sg   = (tid >> 6) * 4 + (lane >> 4);   // 0..15 subgroup id
    int fl   = lane & 15;                      // feature lane: bf16 4*fl..4*fl+3
    int s  = binStart[bin];
    int e1 = binStart[bin + 1];

    #define EDGE_P(EE)                                                            \
        {                                                                         \
            unsigned pr = ebuf[(EE)];                                             \
            int r  = (int)(pr & ROWMASK);                                         \
            int cl = (int)(pr >> 24);                                             \
            float dr = dinv[r];                                                   \
            ushort4 v = *(const ushort4*)(h + (size_t)r * OUT_F + fl * 4);        \
            float* ap = accum + cl * OUT_F + fl;                                  \
            atomicAdd(ap +  0, bf2f(v.x) * dr);                                   \
            atomicAdd(ap + 16, bf2f(v.y) * dr);                                   \
            atomicAdd(ap + 32, bf2f(v.z) * dr);                                   \
            atomicAdd(ap + 48, bf2f(v.w) * dr);                                   \
        }

    int e = s + sg;
    for (; e + 48 < e1; e += 64) {
        EDGE_P(e);
        EDGE_P(e + 16);
        EDGE_P(e + 32);
        EDGE_P(e + 48);
    }
    for (; e < e1; e += 16) EDGE_P(e);
    #undef EDGE_P

    __syncthreads();

    // epilogue: out[lo+node] = dinv*(accum + dinv*h_self) + b
    for (int i = tid; i < wcnt * 16; i += 256) {
        int node = i >> 4, q = i & 15;
        float dc = dinv[lo + node];
        ushort4 hv = *(const ushort4*)(h + (size_t)(lo + node) * OUT_F + q * 4);
        float4 bv = ((const float4*)b)[q];
        const float* ac = accum + node * OUT_F;
        float4 o;
        o.x = (ac[q]      + bf2f(hv.x) * dc) * dc + bv.x;   // f=4q+0 -> j=0
        o.y = (ac[16 + q] + bf2f(hv.y) * dc) * dc + bv.y;   // j=1
        o.z = (ac[32 + q] + bf2f(hv.z) * dc) * dc + bv.z;   // j=2
        o.w = (ac[48 + q] + bf2f(hv.w) * dc) * dc + bv.w;   // j=3
        *(float4*)(out + (size_t)(lo + node) * OUT_F + q * 4) = o;
    }
}

extern "C" void kernel_launch(void* const* d_in, const int* in_sizes, int n_in,
                              void* d_out, int out_size, void* d_ws, size_t ws_size,
                              hipStream_t stream) {
    const float* x  = (const float*)d_in[0];
    const int*   ei = (const int*)d_in[1];
    const float* W  = (const float*)d_in[2];
    const float* b  = (const float*)d_in[3];
    float* out = (float*)d_out;

    int n = in_sizes[0] / IN_F;
    int E = in_sizes[1] / 2;
    const int* rowp = ei;       // edge_index[0] = source
    const int* colp = ei + E;   // edge_index[1] = target

    int nbins = (n + 255) >> WBITS;   // 391 for n=100000 (<= MAXBINS)

    // workspace layout
    char* wp = (char*)d_ws;
    ushort_t* h    = (ushort_t*)wp;                   // n*64 bf16 = 12.8 MB
    unsigned* ebuf = (unsigned*)(wp + (size_t)n * OUT_F * 2);   // E uint32 = 6.4 MB
    ushort_t* wfrag = (ushort_t*)(ebuf + E);          // 32 KB (16B-aligned)
    float* dinv    = (float*)(wfrag + 16384);         // n f32
    int* binCnt    = (int*)(dinv + n);                // MAXBINS int
    int* binStart  = binCnt + MAXBINS;                // MAXBINS+1 int
    int* binCursor = binStart + MAXBINS + 1;          // MAXBINS int

    int gemmBlocks = (n + 63) / 64;

    hipMemsetAsync(binCnt, 0, MAXBINS * sizeof(int), stream);
    init_kernel<<<512, 256, 0, stream>>>(W, wfrag, colp, binCnt, E, nbins);
    bin_scan_kernel<<<1, 512, 0, stream>>>(binCnt, binStart, binCursor, nbins);
    mega_kernel<<<gemmBlocks + SCAT_BLOCKS, 256, 0, stream>>>(x, wfrag, h, rowp, colp,
                                                              binCursor, ebuf, n, E, nbins,
                                                              gemmBlocks);
    fine_deg_kernel<<<nbins, 256, 0, stream>>>(ebuf, binStart, dinv, n);
    aggregate_kernel<<<nbins, 256, 0, stream>>>(ebuf, binStart, h, dinv, b, out, n);
}

// Round 14
// 139.993 us; speedup vs baseline: 5.4946x; 5.4946x over previous
//
#include <hip/hip_runtime.h>

// GCNConv: out = D^-1/2 (A + I) D^-1/2 (x W) + b
// x: [N,256] f32, edge_index: [2,E] int, W: [256,64] f32, b: [64] f32
// out: [N,64] f32
//
// Best-measured structure (round 10) + validated deltas:
// init (wfrag+hist) -> bin_scan -> mega (GEMM blocks first, 512 scatter blocks)
// -> fine_build (CSR, no g-scaling) -> gather (8-subgroup uint4, dinv per edge).

#define IN_F 256
#define OUT_F 64
#define WBITS 8                  // fine window = 256 nodes per coarse bin
#define MAXBINS 512
#define ROWMASK 0xFFFFFFu        // n < 2^24
#define SCAT_BLOCKS 512

typedef unsigned short ushort_t;
typedef short bf16x8 __attribute__((ext_vector_type(8)));
typedef float f32x4 __attribute__((ext_vector_type(4)));

static __device__ __forceinline__ unsigned f2bf1(float f) {
    unsigned u = __float_as_uint(f);
    return (u + 0x7FFFu + ((u >> 16) & 1u)) >> 16;   // RNE
}
static __device__ __forceinline__ unsigned pk2(float a, float b) {
    return f2bf1(a) | (f2bf1(b) << 16);
}
static __device__ __forceinline__ ushort_t f2bf(float f) { return (ushort_t)f2bf1(f); }
static __device__ __forceinline__ float bf2f(ushort_t h) {
    return __uint_as_float(((unsigned)h) << 16);
}

// --- K1: wfrag pack (first 2048 threads) + coarse bin histogram (all blocks) ---
__global__ __launch_bounds__(256) void init_kernel(const float* __restrict__ W,
                                                   ushort_t* __restrict__ wfrag,
                                                   const int* __restrict__ col,
                                                   int* __restrict__ binCnt,
                                                   int E, int nbins) {
    int gt = blockIdx.x * 256 + threadIdx.x;
    if (gt < 2048) {   // W fragment pack: slot t=(kk*4+ct)*64+l
        int t = gt;
        int kk = t >> 8;
        int ct = (t >> 6) & 3;
        int l  = t & 63;
        int k0 = kk * 32 + (l >> 4) * 8;
        int c  = ct * 16 + (l & 15);
        unsigned u0 = pk2(W[(k0 + 0) * OUT_F + c], W[(k0 + 1) * OUT_F + c]);
        unsigned u1 = pk2(W[(k0 + 2) * OUT_F + c], W[(k0 + 3) * OUT_F + c]);
        unsigned u2 = pk2(W[(k0 + 4) * OUT_F + c], W[(k0 + 5) * OUT_F + c]);
        unsigned u3 = pk2(W[(k0 + 6) * OUT_F + c], W[(k0 + 7) * OUT_F + c]);
        ((uint4*)wfrag)[t] = make_uint4(u0, u1, u2, u3);
    }
    __shared__ int hist[MAXBINS];
    int tid = threadIdx.x;
    for (int i = tid; i < nbins; i += 256) hist[i] = 0;
    __syncthreads();
    int stride = gridDim.x * 256;
    for (int e = blockIdx.x * 256 + tid; e < E; e += stride)
        atomicAdd(&hist[col[e] >> WBITS], 1);
    __syncthreads();
    for (int i = tid; i < nbins; i += 256)
        if (hist[i]) atomicAdd(&binCnt[i], hist[i]);
}

// --- K2: exclusive scan of binCnt -> binStart, binCursor; start[n] = E ---
__global__ void bin_scan_kernel(const int* __restrict__ binCnt, int* __restrict__ binStart,
                                int* __restrict__ binCursor, int* __restrict__ start_n,
                                int nbins) {
    __shared__ int lds[512];
    int tid = threadIdx.x;   // 512 threads
    int v = (tid < nbins) ? binCnt[tid] : 0;
    lds[tid] = v;
    __syncthreads();
    for (int d = 1; d < 512; d <<= 1) {
        int t = (tid >= d) ? lds[tid - d] : 0;
        __syncthreads();
        lds[tid] += t;
        __syncthreads();
    }
    if (tid < nbins) {
        int ex = lds[tid] - v;
        binStart[tid] = ex;
        binCursor[tid] = ex;
    }
    if (tid == 511) {
        binStart[nbins] = lds[511];   // = E
        start_n[0] = lds[511];        // start[n] = E
    }
}

// --- K3 MEGA: blocks [0,gemmBlocks) = MFMA GEMM h=xW (bf16, unscaled);
//              blocks [gemmBlocks, +SCAT_BLOCKS) = coarse scatter ---
__global__ __launch_bounds__(256) void mega_kernel(const float* __restrict__ x,
                                                   const ushort_t* __restrict__ wfrag,
                                                   ushort_t* __restrict__ h,
                                                   const int* __restrict__ row,
                                                   const int* __restrict__ col,
                                                   int* __restrict__ binCursor,
                                                   unsigned* __restrict__ ebuf,
                                                   int n, int E, int nbins, int gemmBlocks) {
    __shared__ int cnt[MAXBINS];
    __shared__ int cur[MAXBINS];
    int tid = threadIdx.x;

    if (blockIdx.x < gemmBlocks) {
        // ---------------- GEMM path ----------------
        int l  = tid & 63;
        int lr = l & 15;
        int lg = l >> 4;
        int rowbase = blockIdx.x * 64 + (tid >> 6) * 16;
        int arow = rowbase + lr;
        int lrow = (arow < n) ? arow : (n - 1);
        const float* xp = x + (size_t)lrow * IN_F + lg * 8;
        const uint4* wf = (const uint4*)wfrag;

        f32x4 acc0 = {0.f, 0.f, 0.f, 0.f};
        f32x4 acc1 = {0.f, 0.f, 0.f, 0.f};
        f32x4 acc2 = {0.f, 0.f, 0.f, 0.f};
        f32x4 acc3 = {0.f, 0.f, 0.f, 0.f};

        #pragma unroll
        for (int kk = 0; kk < 8; ++kk) {
            float4 xa = *(const float4*)(xp + kk * 32);
            float4 xb = *(const float4*)(xp + kk * 32 + 4);
            union { bf16x8 v; unsigned u[4]; } A;
            A.u[0] = pk2(xa.x, xa.y);
            A.u[1] = pk2(xa.z, xa.w);
            A.u[2] = pk2(xb.x, xb.y);
            A.u[3] = pk2(xb.z, xb.w);
            union { uint4 q; bf16x8 v; } B0, B1, B2, B3;
            B0.q = wf[(kk * 4 + 0) * 64 + l];
            B1.q = wf[(kk * 4 + 1) * 64 + l];
            B2.q = wf[(kk * 4 + 2) * 64 + l];
            B3.q = wf[(kk * 4 + 3) * 64 + l];
            acc0 = __builtin_amdgcn_mfma_f32_16x16x32_bf16(A.v, B0.v, acc0, 0, 0, 0);
            acc1 = __builtin_amdgcn_mfma_f32_16x16x32_bf16(A.v, B1.v, acc1, 0, 0, 0);
            acc2 = __builtin_amdgcn_mfma_f32_16x16x32_bf16(A.v, B2.v, acc2, 0, 0, 0);
            acc3 = __builtin_amdgcn_mfma_f32_16x16x32_bf16(A.v, B3.v, acc3, 0, 0, 0);
        }

        #pragma unroll
        for (int q = 0; q < 4; ++q) {
            int r = rowbase + lg * 4 + q;
            if (r < n) {
                ushort_t* gp = h + (size_t)r * OUT_F + lr;
                gp[0]  = f2bf(acc0[q]);
                gp[16] = f2bf(acc1[q]);
                gp[32] = f2bf(acc2[q]);
                gp[48] = f2bf(acc3[q]);
            }
        }
    } else {
        // ---------------- coarse scatter path ----------------
        int sb = blockIdx.x - gemmBlocks;   // 0..SCAT_BLOCKS-1
        for (int i = tid; i < nbins; i += 256) cnt[i] = 0;
        __syncthreads();
        int chunk = (E + SCAT_BLOCKS - 1) / SCAT_BLOCKS;
        int s = sb * chunk;
        int epos = min(E, s + chunk);
        for (int e = s + tid; e < epos; e += 256)
            atomicAdd(&cnt[col[e] >> WBITS], 1);
        __syncthreads();
        for (int i = tid; i < nbins; i += 256) {
            int c = cnt[i];
            cur[i] = c ? atomicAdd(&binCursor[i], c) : 0;
        }
        __syncthreads();
        for (int e = s + tid; e < epos; e += 256) {
            int cc = col[e];
            int pos = atomicAdd(&cur[cc >> WBITS], 1);
            ebuf[pos] = (unsigned)row[e] | ((unsigned)(cc & ((1 << WBITS) - 1)) << 24);
        }
    }
}

// --- K4: per-bin fine CSR build (deg/dinv/start/bucket), LDS-local ---
__global__ __launch_bounds__(256) void fine_build_kernel(const unsigned* __restrict__ ebuf,
                                                         const int* __restrict__ binStart,
                                                         int* __restrict__ start,
                                                         float* __restrict__ dinv,
                                                         int* __restrict__ bucket, int n) {
    __shared__ int sdeg[256];
    __shared__ int scur[256];
    int b = blockIdx.x;
    int lo = b << WBITS;
    int wcnt = min(256, n - lo);
    int tid = threadIdx.x;
    sdeg[tid] = 0;
    __syncthreads();
    int s = binStart[b], epos = binStart[b + 1];
    for (int e = s + tid; e < epos; e += 256)
        atomicAdd(&sdeg[ebuf[e] >> 24], 1);
    __syncthreads();
    int d = sdeg[tid];
    if (tid < wcnt) dinv[lo + tid] = rsqrtf((float)(d + 1));
    for (int dd = 1; dd < 256; dd <<= 1) {
        int t = (tid >= dd) ? sdeg[tid - dd] : 0;
        __syncthreads();
        sdeg[tid] += t;
        __syncthreads();
    }
    int ex = sdeg[tid] - d;
    if (tid < wcnt) start[lo + tid] = s + ex;
    scur[tid] = ex;
    __syncthreads();
    for (int e = s + tid; e < epos; e += 256) {
        unsigned pr = ebuf[e];
        int pos = atomicAdd(&scur[pr >> 24], 1);
        bucket[s + pos] = (int)(pr & ROWMASK);
    }
}

// --- K5: out[c] = dinv[c] * (sum_j h[src_j]*dinv[src_j] + h[c]*dinv[c]) + b ---
// Wave = 1 node; 8 subgroups of 8 lanes walk different edges; lane holds
// 8 features (16 B uint4). One VMEM issue = 8 edge-rows; unroll-2 => 16 in flight.
__global__ __launch_bounds__(256) void gather_kernel(const int* __restrict__ start,
                              const int* __restrict__ bucket, const ushort_t* __restrict__ h,
                              const float* __restrict__ dinv, const float* __restrict__ b,
                              float* __restrict__ out, int n) {
    int lane = threadIdx.x & 63;
    int node = blockIdx.x * 4 + (threadIdx.x >> 6);
    if (node >= n) return;
    int f8  = lane & 7;         // features 8*f8 .. 8*f8+7
    int grp = lane >> 3;        // edge subgroup 0..7
    int s0  = start[node];
    int cnt = start[node + 1] - s0;
    const int* bp = bucket + s0;
    int last = cnt - 1;

    float a0 = 0.f, a1 = 0.f, a2 = 0.f, a3 = 0.f;
    float a4 = 0.f, a5 = 0.f, a6 = 0.f, a7 = 0.f;
    union { uint4 q; ushort_t s[8]; } VA, VB;
    for (int e0 = 0; e0 < cnt; e0 += 16) {
        int eA = e0 + grp;
        int eB = e0 + 8 + grp;
        int iA = bp[min(eA, last)];
        int iB = bp[min(eB, last)];
        VA.q = *(const uint4*)(h + (size_t)iA * OUT_F + f8 * 8);
        VB.q = *(const uint4*)(h + (size_t)iB * OUT_F + f8 * 8);
        float dA = (eA < cnt) ? dinv[iA] : 0.f;
        float dB = (eB < cnt) ? dinv[iB] : 0.f;
        a0 += bf2f(VA.s[0]) * dA;
        a1 += bf2f(VA.s[1]) * dA;
        a2 += bf2f(VA.s[2]) * dA;
        a3 += bf2f(VA.s[3]) * dA;
        a4 += bf2f(VA.s[4]) * dA;
        a5 += bf2f(VA.s[5]) * dA;
        a6 += bf2f(VA.s[6]) * dA;
        a7 += bf2f(VA.s[7]) * dA;
        a0 += bf2f(VB.s[0]) * dB;
        a1 += bf2f(VB.s[1]) * dB;
        a2 += bf2f(VB.s[2]) * dB;
        a3 += bf2f(VB.s[3]) * dB;
        a4 += bf2f(VB.s[4]) * dB;
        a5 += bf2f(VB.s[5]) * dB;
        a6 += bf2f(VB.s[6]) * dB;
        a7 += bf2f(VB.s[7]) * dB;
    }
    // cross-subgroup reduce: lanes f8, f8+8, ..., f8+56 hold the same features
    #pragma unroll
    for (int off = 8; off < 64; off <<= 1) {
        a0 += __shfl_xor(a0, off, 64);
        a1 += __shfl_xor(a1, off, 64);
        a2 += __shfl_xor(a2, off, 64);
        a3 += __shfl_xor(a3, off, 64);
        a4 += __shfl_xor(a4, off, 64);
        a5 += __shfl_xor(a5, off, 64);
        a6 += __shfl_xor(a6, off, 64);
        a7 += __shfl_xor(a7, off, 64);
    }

    if (grp == 0) {
        union { uint4 q; ushort_t s[8]; } SV;
        SV.q = *(const uint4*)(h + (size_t)node * OUT_F + f8 * 8);
        float dc = dinv[node];
        const float4* bv = (const float4*)b;
        float4 o0, o1;
        o0.x = (a0 + bf2f(SV.s[0]) * dc) * dc + bv[f8 * 2].x;
        o0.y = (a1 + bf2f(SV.s[1]) * dc) * dc + bv[f8 * 2].y;
        o0.z = (a2 + bf2f(SV.s[2]) * dc) * dc + bv[f8 * 2].z;
        o0.w = (a3 + bf2f(SV.s[3]) * dc) * dc + bv[f8 * 2].w;
        o1.x = (a4 + bf2f(SV.s[4]) * dc) * dc + bv[f8 * 2 + 1].x;
        o1.y = (a5 + bf2f(SV.s[5]) * dc) * dc + bv[f8 * 2 + 1].y;
        o1.z = (a6 + bf2f(SV.s[6]) * dc) * dc + bv[f8 * 2 + 1].z;
        o1.w = (a7 + bf2f(SV.s[7]) * dc) * dc + bv[f8 * 2 + 1].w;
        float4* op = (float4*)(out + (size_t)node * OUT_F + f8 * 8);
        op[0] = o0;
        op[1] = o1;
    }
}

extern "C" void kernel_launch(void* const* d_in, const int* in_sizes, int n_in,
                              void* d_out, int out_size, void* d_ws, size_t ws_size,
                              hipStream_t stream) {
    const float* x  = (const float*)d_in[0];
    const int*   ei = (const int*)d_in[1];
    const float* W  = (const float*)d_in[2];
    const float* b  = (const float*)d_in[3];
    float* out = (float*)d_out;

    int n = in_sizes[0] / IN_F;
    int E = in_sizes[1] / 2;
    const int* rowp = ei;       // edge_index[0] = source
    const int* colp = ei + E;   // edge_index[1] = target

    int nbins = (n + 255) >> WBITS;   // 391 for n=100000 (<= MAXBINS)

    // workspace layout (no aliasing: ebuf live concurrently with h writes)
    char* wp = (char*)d_ws;
    ushort_t* h    = (ushort_t*)wp;                   // n*64 bf16 = 12.8 MB
    unsigned* ebuf = (unsigned*)(wp + (size_t)n * OUT_F * 2);   // E uint32 = 6.4 MB
    int* bucket    = (int*)(ebuf + E);                // E int = 6.4 MB
    ushort_t* wfrag = (ushort_t*)(bucket + E);        // 32 KB (16B-aligned)
    int* start     = (int*)(wfrag + 16384);           // (n+1) int
    float* dinv    = (float*)(start + n + 1);         // n f32
    int* binCnt    = (int*)(dinv + n);                // MAXBINS int
    int* binStart  = binCnt + MAXBINS;                // MAXBINS+1 int
    int* binCursor = binStart + MAXBINS + 1;          // MAXBINS int

    int gemmBlocks = (n + 63) / 64;

    hipMemsetAsync(binCnt, 0, MAXBINS * sizeof(int), stream);
    init_kernel<<<512, 256, 0, stream>>>(W, wfrag, colp, binCnt, E, nbins);
    bin_scan_kernel<<<1, 512, 0, stream>>>(binCnt, binStart, binCursor, start + n, nbins);
    mega_kernel<<<gemmBlocks + SCAT_BLOCKS, 256, 0, stream>>>(x, wfrag, h, rowp, colp,
                                                              binCursor, ebuf, n, E, nbins,
                                                              gemmBlocks);
    fine_build_kernel<<<nbins, 256, 0, stream>>>(ebuf, binStart, start, dinv, bucket, n);
    gather_kernel<<<(n + 3) / 4, 256, 0, stream>>>(start, bucket, h, dinv, b, out, n);
}

// Round 15
// 137.392 us; speedup vs baseline: 5.5987x; 1.0189x over previous
//
#include <hip/hip_runtime.h>

// GCNConv: out = D^-1/2 (A + I) D^-1/2 (x W) + b
// x: [N,256] f32, edge_index: [2,E] int, W: [256,64] f32, b: [64] f32
// out: [N,64] f32
//
// init (wfrag+hist) -> bin_scan -> mega (GEMM blocks first, 512 scatter blocks)
// -> fine_build (CSR, 512-node bins) -> gather (8-subgroup uint4, dinv per edge).

#define IN_F 256
#define OUT_F 64
#define WBITS 9                  // fine window = 512 nodes per coarse bin
#define MAXBINS 256
#define CSHIFT 23                // packed: row | (col_local << 23)
#define ROWMASK 0x7FFFFFu        // n < 2^23
#define SCAT_BLOCKS 512

typedef unsigned short ushort_t;
typedef short bf16x8 __attribute__((ext_vector_type(8)));
typedef float f32x4 __attribute__((ext_vector_type(4)));

static __device__ __forceinline__ unsigned f2bf1(float f) {
    unsigned u = __float_as_uint(f);
    return (u + 0x7FFFu + ((u >> 16) & 1u)) >> 16;   // RNE
}
static __device__ __forceinline__ unsigned pk2(float a, float b) {
    return f2bf1(a) | (f2bf1(b) << 16);
}
static __device__ __forceinline__ ushort_t f2bf(float f) { return (ushort_t)f2bf1(f); }
static __device__ __forceinline__ float bf2f(ushort_t h) {
    return __uint_as_float(((unsigned)h) << 16);
}

// --- K1: wfrag pack (first 2048 threads) + coarse bin histogram (all blocks) ---
__global__ __launch_bounds__(256) void init_kernel(const float* __restrict__ W,
                                                   ushort_t* __restrict__ wfrag,
                                                   const int* __restrict__ col,
                                                   int* __restrict__ binCnt,
                                                   int E, int nbins) {
    int gt = blockIdx.x * 256 + threadIdx.x;
    if (gt < 2048) {   // W fragment pack: slot t=(kk*4+ct)*64+l
        int t = gt;
        int kk = t >> 8;
        int ct = (t >> 6) & 3;
        int l  = t & 63;
        int k0 = kk * 32 + (l >> 4) * 8;
        int c  = ct * 16 + (l & 15);
        unsigned u0 = pk2(W[(k0 + 0) * OUT_F + c], W[(k0 + 1) * OUT_F + c]);
        unsigned u1 = pk2(W[(k0 + 2) * OUT_F + c], W[(k0 + 3) * OUT_F + c]);
        unsigned u2 = pk2(W[(k0 + 4) * OUT_F + c], W[(k0 + 5) * OUT_F + c]);
        unsigned u3 = pk2(W[(k0 + 6) * OUT_F + c], W[(k0 + 7) * OUT_F + c]);
        ((uint4*)wfrag)[t] = make_uint4(u0, u1, u2, u3);
    }
    __shared__ int hist[MAXBINS];
    int tid = threadIdx.x;
    if (tid < nbins) hist[tid] = 0;
    __syncthreads();
    int stride = gridDim.x * 256;
    for (int e = blockIdx.x * 256 + tid; e < E; e += stride)
        atomicAdd(&hist[col[e] >> WBITS], 1);
    __syncthreads();
    if (tid < nbins && hist[tid]) atomicAdd(&binCnt[tid], hist[tid]);
}

// --- K2: exclusive scan of binCnt -> binStart, binCursor; start[n] = E ---
__global__ void bin_scan_kernel(const int* __restrict__ binCnt, int* __restrict__ binStart,
                                int* __restrict__ binCursor, int* __restrict__ start_n,
                                int nbins) {
    __shared__ int lds[MAXBINS];
    int tid = threadIdx.x;   // MAXBINS threads
    int v = (tid < nbins) ? binCnt[tid] : 0;
    lds[tid] = v;
    __syncthreads();
    for (int d = 1; d < MAXBINS; d <<= 1) {
        int t = (tid >= d) ? lds[tid - d] : 0;
        __syncthreads();
        lds[tid] += t;
        __syncthreads();
    }
    if (tid < nbins) {
        int ex = lds[tid] - v;
        binStart[tid] = ex;
        binCursor[tid] = ex;
    }
    if (tid == MAXBINS - 1) {
        binStart[nbins] = lds[MAXBINS - 1];   // = E
        start_n[0] = lds[MAXBINS - 1];        // start[n] = E
    }
}

// --- K3 MEGA: blocks [0,gemmBlocks) = MFMA GEMM h=xW (bf16, unscaled);
//              blocks [gemmBlocks, +SCAT_BLOCKS) = coarse scatter ---
__global__ __launch_bounds__(256) void mega_kernel(const float* __restrict__ x,
                                                   const ushort_t* __restrict__ wfrag,
                                                   ushort_t* __restrict__ h,
                                                   const int* __restrict__ row,
                                                   const int* __restrict__ col,
                                                   int* __restrict__ binCursor,
                                                   unsigned* __restrict__ ebuf,
                                                   int n, int E, int nbins, int gemmBlocks) {
    __shared__ int cnt[MAXBINS];
    __shared__ int cur[MAXBINS];
    int tid = threadIdx.x;

    if (blockIdx.x < gemmBlocks) {
        // ---------------- GEMM path ----------------
        int l  = tid & 63;
        int lr = l & 15;
        int lg = l >> 4;
        int rowbase = blockIdx.x * 64 + (tid >> 6) * 16;
        int arow = rowbase + lr;
        int lrow = (arow < n) ? arow : (n - 1);
        const float* xp = x + (size_t)lrow * IN_F + lg * 8;
        const uint4* wf = (const uint4*)wfrag;

        f32x4 acc0 = {0.f, 0.f, 0.f, 0.f};
        f32x4 acc1 = {0.f, 0.f, 0.f, 0.f};
        f32x4 acc2 = {0.f, 0.f, 0.f, 0.f};
        f32x4 acc3 = {0.f, 0.f, 0.f, 0.f};

        #pragma unroll
        for (int kk = 0; kk < 8; ++kk) {
            float4 xa = *(const float4*)(xp + kk * 32);
            float4 xb = *(const float4*)(xp + kk * 32 + 4);
            union { bf16x8 v; unsigned u[4]; } A;
            A.u[0] = pk2(xa.x, xa.y);
            A.u[1] = pk2(xa.z, xa.w);
            A.u[2] = pk2(xb.x, xb.y);
            A.u[3] = pk2(xb.z, xb.w);
            union { uint4 q; bf16x8 v; } B0, B1, B2, B3;
            B0.q = wf[(kk * 4 + 0) * 64 + l];
            B1.q = wf[(kk * 4 + 1) * 64 + l];
            B2.q = wf[(kk * 4 + 2) * 64 + l];
            B3.q = wf[(kk * 4 + 3) * 64 + l];
            acc0 = __builtin_amdgcn_mfma_f32_16x16x32_bf16(A.v, B0.v, acc0, 0, 0, 0);
            acc1 = __builtin_amdgcn_mfma_f32_16x16x32_bf16(A.v, B1.v, acc1, 0, 0, 0);
            acc2 = __builtin_amdgcn_mfma_f32_16x16x32_bf16(A.v, B2.v, acc2, 0, 0, 0);
            acc3 = __builtin_amdgcn_mfma_f32_16x16x32_bf16(A.v, B3.v, acc3, 0, 0, 0);
        }

        #pragma unroll
        for (int q = 0; q < 4; ++q) {
            int r = rowbase + lg * 4 + q;
            if (r < n) {
                ushort_t* gp = h + (size_t)r * OUT_F + lr;
                gp[0]  = f2bf(acc0[q]);
                gp[16] = f2bf(acc1[q]);
                gp[32] = f2bf(acc2[q]);
                gp[48] = f2bf(acc3[q]);
            }
        }
    } else {
        // ---------------- coarse scatter path ----------------
        int sb = blockIdx.x - gemmBlocks;   // 0..SCAT_BLOCKS-1
        if (tid < nbins) cnt[tid] = 0;
        __syncthreads();
        int chunk = (E + SCAT_BLOCKS - 1) / SCAT_BLOCKS;
        int s = sb * chunk;
        int epos = min(E, s + chunk);
        for (int e = s + tid; e < epos; e += 256)
            atomicAdd(&cnt[col[e] >> WBITS], 1);
        __syncthreads();
        if (tid < nbins) {
            int c = cnt[tid];
            cur[tid] = c ? atomicAdd(&binCursor[tid], c) : 0;
        }
        __syncthreads();
        for (int e = s + tid; e < epos; e += 256) {
            int cc = col[e];
            int pos = atomicAdd(&cur[cc >> WBITS], 1);
            ebuf[pos] = (unsigned)row[e] | ((unsigned)(cc & ((1 << WBITS) - 1)) << CSHIFT);
        }
    }
}

// --- K4: per-bin fine CSR build (deg/dinv/start/bucket), 512-node bins ---
__global__ __launch_bounds__(512) void fine_build_kernel(const unsigned* __restrict__ ebuf,
                                                         const int* __restrict__ binStart,
                                                         int* __restrict__ start,
                                                         float* __restrict__ dinv,
                                                         int* __restrict__ bucket, int n) {
    __shared__ int sdeg[512];
    __shared__ int scur[512];
    int b = blockIdx.x;
    int lo = b << WBITS;
    int wcnt = min(512, n - lo);
    int tid = threadIdx.x;
    sdeg[tid] = 0;
    __syncthreads();
    int s = binStart[b], epos = binStart[b + 1];
    for (int e = s + tid; e < epos; e += 512)
        atomicAdd(&sdeg[ebuf[e] >> CSHIFT], 1);
    __syncthreads();
    int d = sdeg[tid];
    if (tid < wcnt) dinv[lo + tid] = rsqrtf((float)(d + 1));
    for (int dd = 1; dd < 512; dd <<= 1) {
        int t = (tid >= dd) ? sdeg[tid - dd] : 0;
        __syncthreads();
        sdeg[tid] += t;
        __syncthreads();
    }
    int ex = sdeg[tid] - d;
    if (tid < wcnt) start[lo + tid] = s + ex;
    scur[tid] = ex;
    __syncthreads();
    for (int e = s + tid; e < epos; e += 512) {
        unsigned pr = ebuf[e];
        int pos = atomicAdd(&scur[pr >> CSHIFT], 1);
        bucket[s + pos] = (int)(pr & ROWMASK);
    }
}

// --- K5: out[c] = dinv[c] * (sum_j h[src_j]*dinv[src_j] + h[c]*dinv[c]) + b ---
// Wave = 1 node; 8 subgroups of 8 lanes walk different edges; lane holds
// 8 features (16 B uint4). One VMEM issue = 8 edge-rows; unroll-2 => 16 in flight.
__global__ __launch_bounds__(256) void gather_kernel(const int* __restrict__ start,
                              const int* __restrict__ bucket, const ushort_t* __restrict__ h,
                              const float* __restrict__ dinv, const float* __restrict__ b,
                              float* __restrict__ out, int n) {
    int lane = threadIdx.x & 63;
    int node = blockIdx.x * 4 + (threadIdx.x >> 6);
    if (node >= n) return;
    int f8  = lane & 7;         // features 8*f8 .. 8*f8+7
    int grp = lane >> 3;        // edge subgroup 0..7
    int s0  = start[node];
    int cnt = start[node + 1] - s0;
    const int* bp = bucket + s0;
    int last = cnt - 1;

    float a0 = 0.f, a1 = 0.f, a2 = 0.f, a3 = 0.f;
    float a4 = 0.f, a5 = 0.f, a6 = 0.f, a7 = 0.f;
    union { uint4 q; ushort_t s[8]; } VA, VB;
    for (int e0 = 0; e0 < cnt; e0 += 16) {
        int eA = e0 + grp;
        int eB = e0 + 8 + grp;
        int iA = bp[min(eA, last)];
        int iB = bp[min(eB, last)];
        VA.q = *(const uint4*)(h + (size_t)iA * OUT_F + f8 * 8);
        VB.q = *(const uint4*)(h + (size_t)iB * OUT_F + f8 * 8);
        float dA = (eA < cnt) ? dinv[iA] : 0.f;
        float dB = (eB < cnt) ? dinv[iB] : 0.f;
        a0 += bf2f(VA.s[0]) * dA;
        a1 += bf2f(VA.s[1]) * dA;
        a2 += bf2f(VA.s[2]) * dA;
        a3 += bf2f(VA.s[3]) * dA;
        a4 += bf2f(VA.s[4]) * dA;
        a5 += bf2f(VA.s[5]) * dA;
        a6 += bf2f(VA.s[6]) * dA;
        a7 += bf2f(VA.s[7]) * dA;
        a0 += bf2f(VB.s[0]) * dB;
        a1 += bf2f(VB.s[1]) * dB;
        a2 += bf2f(VB.s[2]) * dB;
        a3 += bf2f(VB.s[3]) * dB;
        a4 += bf2f(VB.s[4]) * dB;
        a5 += bf2f(VB.s[5]) * dB;
        a6 += bf2f(VB.s[6]) * dB;
        a7 += bf2f(VB.s[7]) * dB;
    }
    // cross-subgroup reduce: lanes f8, f8+8, ..., f8+56 hold the same features
    #pragma unroll
    for (int off = 8; off < 64; off <<= 1) {
        a0 += __shfl_xor(a0, off, 64);
        a1 += __shfl_xor(a1, off, 64);
        a2 += __shfl_xor(a2, off, 64);
        a3 += __shfl_xor(a3, off, 64);
        a4 += __shfl_xor(a4, off, 64);
        a5 += __shfl_xor(a5, off, 64);
        a6 += __shfl_xor(a6, off, 64);
        a7 += __shfl_xor(a7, off, 64);
    }

    if (grp == 0) {
        union { uint4 q; ushort_t s[8]; } SV;
        SV.q = *(const uint4*)(h + (size_t)node * OUT_F + f8 * 8);
        float dc = dinv[node];
        const float4* bv = (const float4*)b;
        float4 o0, o1;
        o0.x = (a0 + bf2f(SV.s[0]) * dc) * dc + bv[f8 * 2].x;
        o0.y = (a1 + bf2f(SV.s[1]) * dc) * dc + bv[f8 * 2].y;
        o0.z = (a2 + bf2f(SV.s[2]) * dc) * dc + bv[f8 * 2].z;
        o0.w = (a3 + bf2f(SV.s[3]) * dc) * dc + bv[f8 * 2].w;
        o1.x = (a4 + bf2f(SV.s[4]) * dc) * dc + bv[f8 * 2 + 1].x;
        o1.y = (a5 + bf2f(SV.s[5]) * dc) * dc + bv[f8 * 2 + 1].y;
        o1.z = (a6 + bf2f(SV.s[6]) * dc) * dc + bv[f8 * 2 + 1].z;
        o1.w = (a7 + bf2f(SV.s[7]) * dc) * dc + bv[f8 * 2 + 1].w;
        float4* op = (float4*)(out + (size_t)node * OUT_F + f8 * 8);
        op[0] = o0;
        op[1] = o1;
    }
}

extern "C" void kernel_launch(void* const* d_in, const int* in_sizes, int n_in,
                              void* d_out, int out_size, void* d_ws, size_t ws_size,
                              hipStream_t stream) {
    const float* x  = (const float*)d_in[0];
    const int*   ei = (const int*)d_in[1];
    const float* W  = (const float*)d_in[2];
    const float* b  = (const float*)d_in[3];
    float* out = (float*)d_out;

    int n = in_sizes[0] / IN_F;
    int E = in_sizes[1] / 2;
    const int* rowp = ei;       // edge_index[0] = source
    const int* colp = ei + E;   // edge_index[1] = target

    int nbins = (n + (1 << WBITS) - 1) >> WBITS;   // 196 for n=100000 (<= MAXBINS)

    // workspace layout (no aliasing: ebuf live concurrently with h writes)
    char* wp = (char*)d_ws;
    ushort_t* h    = (ushort_t*)wp;                   // n*64 bf16 = 12.8 MB
    unsigned* ebuf = (unsigned*)(wp + (size_t)n * OUT_F * 2);   // E uint32 = 6.4 MB
    int* bucket    = (int*)(ebuf + E);                // E int = 6.4 MB
    ushort_t* wfrag = (ushort_t*)(bucket + E);        // 32 KB (16B-aligned)
    int* start     = (int*)(wfrag + 16384);           // (n+1) int
    float* dinv    = (float*)(start + n + 1);         // n f32
    int* binCnt    = (int*)(dinv + n);                // MAXBINS int
    int* binStart  = binCnt + MAXBINS;                // MAXBINS+1 int
    int* binCursor = binStart + MAXBINS + 1;          // MAXBINS int

    int gemmBlocks = (n + 63) / 64;

    hipMemsetAsync(binCnt, 0, MAXBINS * sizeof(int), stream);
    init_kernel<<<512, 256, 0, stream>>>(W, wfrag, colp, binCnt, E, nbins);
    bin_scan_kernel<<<1, MAXBINS, 0, stream>>>(binCnt, binStart, binCursor, start + n, nbins);
    mega_kernel<<<gemmBlocks + SCAT_BLOCKS, 256, 0, stream>>>(x, wfrag, h, rowp, colp,
                                                              binCursor, ebuf, n, E, nbins,
                                                              gemmBlocks);
    fine_build_kernel<<<nbins, 512, 0, stream>>>(ebuf, binStart, start, dinv, bucket, n);
    gather_kernel<<<(n + 3) / 4, 256, 0, stream>>>(start, bucket, h, dinv, b, out, n);
}

// Round 16
// 133.897 us; speedup vs baseline: 5.7448x; 1.0261x over previous
//
#include <hip/hip_runtime.h>

// GCNConv: out = D^-1/2 (A + I) D^-1/2 (x W) + b
// x: [N,256] f32, edge_index: [2,E] int, W: [256,64] f32, b: [64] f32
// out: [N,64] f32
//
// init (wfrag + per-chunk bin counts + global hist) -> bin_scan ->
// mega (GEMM blocks first; scatter blocks claim from precomputed counts,
// single pass) -> fine_build (CSR, 512-node bins) -> gather (8-subgroup uint4).

#define IN_F 256
#define OUT_F 64
#define WBITS 9                  // fine window = 512 nodes per coarse bin
#define MAXBINS 256
#define CSHIFT 23                // packed: row | (col_local << 23)
#define ROWMASK 0x7FFFFFu        // n < 2^23
#define SCAT_BLOCKS 512

typedef unsigned short ushort_t;
typedef short bf16x8 __attribute__((ext_vector_type(8)));
typedef float f32x4 __attribute__((ext_vector_type(4)));

static __device__ __forceinline__ unsigned f2bf1(float f) {
    unsigned u = __float_as_uint(f);
    return (u + 0x7FFFu + ((u >> 16) & 1u)) >> 16;   // RNE
}
static __device__ __forceinline__ unsigned pk2(float a, float b) {
    return f2bf1(a) | (f2bf1(b) << 16);
}
static __device__ __forceinline__ ushort_t f2bf(float f) { return (ushort_t)f2bf1(f); }
static __device__ __forceinline__ float bf2f(ushort_t h) {
    return __uint_as_float(((unsigned)h) << 16);
}

// --- K1: wfrag pack (first 2048 threads) + per-chunk bin counts + global hist ---
// Block sb counts the SAME contiguous chunk mega's scatter block sb will emit.
__global__ __launch_bounds__(256) void init_kernel(const float* __restrict__ W,
                                                   ushort_t* __restrict__ wfrag,
                                                   const int* __restrict__ col,
                                                   int* __restrict__ binCnt,
                                                   int* __restrict__ partialCnt,
                                                   int E, int nbins) {
    int gt = blockIdx.x * 256 + threadIdx.x;
    if (gt < 2048) {   // W fragment pack: slot t=(kk*4+ct)*64+l
        int t = gt;
        int kk = t >> 8;
        int ct = (t >> 6) & 3;
        int l  = t & 63;
        int k0 = kk * 32 + (l >> 4) * 8;
        int c  = ct * 16 + (l & 15);
        unsigned u0 = pk2(W[(k0 + 0) * OUT_F + c], W[(k0 + 1) * OUT_F + c]);
        unsigned u1 = pk2(W[(k0 + 2) * OUT_F + c], W[(k0 + 3) * OUT_F + c]);
        unsigned u2 = pk2(W[(k0 + 4) * OUT_F + c], W[(k0 + 5) * OUT_F + c]);
        unsigned u3 = pk2(W[(k0 + 6) * OUT_F + c], W[(k0 + 7) * OUT_F + c]);
        ((uint4*)wfrag)[t] = make_uint4(u0, u1, u2, u3);
    }
    __shared__ int hist[MAXBINS];
    int tid = threadIdx.x;
    if (tid < nbins) hist[tid] = 0;
    __syncthreads();
    int chunk = (E + SCAT_BLOCKS - 1) / SCAT_BLOCKS;
    int s = blockIdx.x * chunk;
    int epos = min(E, s + chunk);
    for (int e = s + tid; e < epos; e += 256)
        atomicAdd(&hist[col[e] >> WBITS], 1);
    __syncthreads();
    if (tid < nbins) {
        int c = hist[tid];
        partialCnt[blockIdx.x * MAXBINS + tid] = c;
        if (c) atomicAdd(&binCnt[tid], c);
    }
}

// --- K2: exclusive scan of binCnt -> binStart, binCursor; start[n] = E ---
__global__ void bin_scan_kernel(const int* __restrict__ binCnt, int* __restrict__ binStart,
                                int* __restrict__ binCursor, int* __restrict__ start_n,
                                int nbins) {
    __shared__ int lds[MAXBINS];
    int tid = threadIdx.x;   // MAXBINS threads
    int v = (tid < nbins) ? binCnt[tid] : 0;
    lds[tid] = v;
    __syncthreads();
    for (int d = 1; d < MAXBINS; d <<= 1) {
        int t = (tid >= d) ? lds[tid - d] : 0;
        __syncthreads();
        lds[tid] += t;
        __syncthreads();
    }
    if (tid < nbins) {
        int ex = lds[tid] - v;
        binStart[tid] = ex;
        binCursor[tid] = ex;
    }
    if (tid == MAXBINS - 1) {
        binStart[nbins] = lds[MAXBINS - 1];   // = E
        start_n[0] = lds[MAXBINS - 1];        // start[n] = E
    }
}

// --- K3 MEGA: blocks [0,gemmBlocks) = MFMA GEMM h=xW (bf16, unscaled);
//              blocks [gemmBlocks, +SCAT_BLOCKS) = single-pass coarse scatter ---
__global__ __launch_bounds__(256) void mega_kernel(const float* __restrict__ x,
                                                   const ushort_t* __restrict__ wfrag,
                                                   ushort_t* __restrict__ h,
                                                   const int* __restrict__ row,
                                                   const int* __restrict__ col,
                                                   const int* __restrict__ partialCnt,
                                                   int* __restrict__ binCursor,
                                                   unsigned* __restrict__ ebuf,
                                                   int n, int E, int nbins, int gemmBlocks) {
    __shared__ int cur[MAXBINS];
    int tid = threadIdx.x;

    if (blockIdx.x < gemmBlocks) {
        // ---------------- GEMM path ----------------
        int l  = tid & 63;
        int lr = l & 15;
        int lg = l >> 4;
        int rowbase = blockIdx.x * 64 + (tid >> 6) * 16;
        int arow = rowbase + lr;
        int lrow = (arow < n) ? arow : (n - 1);
        const float* xp = x + (size_t)lrow * IN_F + lg * 8;
        const uint4* wf = (const uint4*)wfrag;

        f32x4 acc0 = {0.f, 0.f, 0.f, 0.f};
        f32x4 acc1 = {0.f, 0.f, 0.f, 0.f};
        f32x4 acc2 = {0.f, 0.f, 0.f, 0.f};
        f32x4 acc3 = {0.f, 0.f, 0.f, 0.f};

        #pragma unroll
        for (int kk = 0; kk < 8; ++kk) {
            float4 xa = *(const float4*)(xp + kk * 32);
            float4 xb = *(const float4*)(xp + kk * 32 + 4);
            union { bf16x8 v; unsigned u[4]; } A;
            A.u[0] = pk2(xa.x, xa.y);
            A.u[1] = pk2(xa.z, xa.w);
            A.u[2] = pk2(xb.x, xb.y);
            A.u[3] = pk2(xb.z, xb.w);
            union { uint4 q; bf16x8 v; } B0, B1, B2, B3;
            B0.q = wf[(kk * 4 + 0) * 64 + l];
            B1.q = wf[(kk * 4 + 1) * 64 + l];
            B2.q = wf[(kk * 4 + 2) * 64 + l];
            B3.q = wf[(kk * 4 + 3) * 64 + l];
            acc0 = __builtin_amdgcn_mfma_f32_16x16x32_bf16(A.v, B0.v, acc0, 0, 0, 0);
            acc1 = __builtin_amdgcn_mfma_f32_16x16x32_bf16(A.v, B1.v, acc1, 0, 0, 0);
            acc2 = __builtin_amdgcn_mfma_f32_16x16x32_bf16(A.v, B2.v, acc2, 0, 0, 0);
            acc3 = __builtin_amdgcn_mfma_f32_16x16x32_bf16(A.v, B3.v, acc3, 0, 0, 0);
        }

        #pragma unroll
        for (int q = 0; q < 4; ++q) {
            int r = rowbase + lg * 4 + q;
            if (r < n) {
                ushort_t* gp = h + (size_t)r * OUT_F + lr;
                gp[0]  = f2bf(acc0[q]);
                gp[16] = f2bf(acc1[q]);
                gp[32] = f2bf(acc2[q]);
                gp[48] = f2bf(acc3[q]);
            }
        }
    } else {
        // ---------------- single-pass scatter (counts precomputed in init) ----
        int sb = blockIdx.x - gemmBlocks;   // 0..SCAT_BLOCKS-1
        if (tid < nbins) {
            int c = partialCnt[sb * MAXBINS + tid];
            cur[tid] = c ? atomicAdd(&binCursor[tid], c) : 0;
        }
        __syncthreads();
        int chunk = (E + SCAT_BLOCKS - 1) / SCAT_BLOCKS;
        int s = sb * chunk;
        int epos = min(E, s + chunk);
        for (int e = s + tid; e < epos; e += 256) {
            int cc = col[e];
            int pos = atomicAdd(&cur[cc >> WBITS], 1);
            ebuf[pos] = (unsigned)row[e] | ((unsigned)(cc & ((1 << WBITS) - 1)) << CSHIFT);
        }
    }
}

// --- K4: per-bin fine CSR build (deg/dinv/start/bucket), 512-node bins ---
__global__ __launch_bounds__(512) void fine_build_kernel(const unsigned* __restrict__ ebuf,
                                                         const int* __restrict__ binStart,
                                                         int* __restrict__ start,
                                                         float* __restrict__ dinv,
                                                         int* __restrict__ bucket, int n) {
    __shared__ int sdeg[512];
    __shared__ int scur[512];
    int b = blockIdx.x;
    int lo = b << WBITS;
    int wcnt = min(512, n - lo);
    int tid = threadIdx.x;
    sdeg[tid] = 0;
    __syncthreads();
    int s = binStart[b], epos = binStart[b + 1];
    for (int e = s + tid; e < epos; e += 512)
        atomicAdd(&sdeg[ebuf[e] >> CSHIFT], 1);
    __syncthreads();
    int d = sdeg[tid];
    if (tid < wcnt) dinv[lo + tid] = rsqrtf((float)(d + 1));
    for (int dd = 1; dd < 512; dd <<= 1) {
        int t = (tid >= dd) ? sdeg[tid - dd] : 0;
        __syncthreads();
        sdeg[tid] += t;
        __syncthreads();
    }
    int ex = sdeg[tid] - d;
    if (tid < wcnt) start[lo + tid] = s + ex;
    scur[tid] = ex;
    __syncthreads();
    for (int e = s + tid; e < epos; e += 512) {
        unsigned pr = ebuf[e];
        int pos = atomicAdd(&scur[pr >> CSHIFT], 1);
        bucket[s + pos] = (int)(pr & ROWMASK);
    }
}

// --- K5: out[c] = dinv[c] * (sum_j h[src_j]*dinv[src_j] + h[c]*dinv[c]) + b ---
// Wave = 1 node; 8 subgroups of 8 lanes walk different edges; lane holds
// 8 features (16 B uint4). One VMEM issue = 8 edge-rows; unroll-2 => 16 in flight.
__global__ __launch_bounds__(256) void gather_kernel(const int* __restrict__ start,
                              const int* __restrict__ bucket, const ushort_t* __restrict__ h,
                              const float* __restrict__ dinv, const float* __restrict__ b,
                              float* __restrict__ out, int n) {
    int lane = threadIdx.x & 63;
    int node = blockIdx.x * 4 + (threadIdx.x >> 6);
    if (node >= n) return;
    int f8  = lane & 7;         // features 8*f8 .. 8*f8+7
    int grp = lane >> 3;        // edge subgroup 0..7
    int s0  = start[node];
    int cnt = start[node + 1] - s0;
    const int* bp = bucket + s0;
    int last = cnt - 1;

    float a0 = 0.f, a1 = 0.f, a2 = 0.f, a3 = 0.f;
    float a4 = 0.f, a5 = 0.f, a6 = 0.f, a7 = 0.f;
    union { uint4 q; ushort_t s[8]; } VA, VB;
    for (int e0 = 0; e0 < cnt; e0 += 16) {
        int eA = e0 + grp;
        int eB = e0 + 8 + grp;
        int iA = bp[min(eA, last)];
        int iB = bp[min(eB, last)];
        VA.q = *(const uint4*)(h + (size_t)iA * OUT_F + f8 * 8);
        VB.q = *(const uint4*)(h + (size_t)iB * OUT_F + f8 * 8);
        float dA = (eA < cnt) ? dinv[iA] : 0.f;
        float dB = (eB < cnt) ? dinv[iB] : 0.f;
        a0 += bf2f(VA.s[0]) * dA;
        a1 += bf2f(VA.s[1]) * dA;
        a2 += bf2f(VA.s[2]) * dA;
        a3 += bf2f(VA.s[3]) * dA;
        a4 += bf2f(VA.s[4]) * dA;
        a5 += bf2f(VA.s[5]) * dA;
        a6 += bf2f(VA.s[6]) * dA;
        a7 += bf2f(VA.s[7]) * dA;
        a0 += bf2f(VB.s[0]) * dB;
        a1 += bf2f(VB.s[1]) * dB;
        a2 += bf2f(VB.s[2]) * dB;
        a3 += bf2f(VB.s[3]) * dB;
        a4 += bf2f(VB.s[4]) * dB;
        a5 += bf2f(VB.s[5]) * dB;
        a6 += bf2f(VB.s[6]) * dB;
        a7 += bf2f(VB.s[7]) * dB;
    }
    // cross-subgroup reduce: lanes f8, f8+8, ..., f8+56 hold the same features
    #pragma unroll
    for (int off = 8; off < 64; off <<= 1) {
        a0 += __shfl_xor(a0, off, 64);
        a1 += __shfl_xor(a1, off, 64);
        a2 += __shfl_xor(a2, off, 64);
        a3 += __shfl_xor(a3, off, 64);
        a4 += __shfl_xor(a4, off, 64);
        a5 += __shfl_xor(a5, off, 64);
        a6 += __shfl_xor(a6, off, 64);
        a7 += __shfl_xor(a7, off, 64);
    }

    if (grp == 0) {
        union { uint4 q; ushort_t s[8]; } SV;
        SV.q = *(const uint4*)(h + (size_t)node * OUT_F + f8 * 8);
        float dc = dinv[node];
        const float4* bv = (const float4*)b;
        float4 o0, o1;
        o0.x = (a0 + bf2f(SV.s[0]) * dc) * dc + bv[f8 * 2].x;
        o0.y = (a1 + bf2f(SV.s[1]) * dc) * dc + bv[f8 * 2].y;
        o0.z = (a2 + bf2f(SV.s[2]) * dc) * dc + bv[f8 * 2].z;
        o0.w = (a3 + bf2f(SV.s[3]) * dc) * dc + bv[f8 * 2].w;
        o1.x = (a4 + bf2f(SV.s[4]) * dc) * dc + bv[f8 * 2 + 1].x;
        o1.y = (a5 + bf2f(SV.s[5]) * dc) * dc + bv[f8 * 2 + 1].y;
        o1.z = (a6 + bf2f(SV.s[6]) * dc) * dc + bv[f8 * 2 + 1].z;
        o1.w = (a7 + bf2f(SV.s[7]) * dc) * dc + bv[f8 * 2 + 1].w;
        float4* op = (float4*)(out + (size_t)node * OUT_F + f8 * 8);
        op[0] = o0;
        op[1] = o1;
    }
}

extern "C" void kernel_launch(void* const* d_in, const int* in_sizes, int n_in,
                              void* d_out, int out_size, void* d_ws, size_t ws_size,
                              hipStream_t stream) {
    const float* x  = (const float*)d_in[0];
    const int*   ei = (const int*)d_in[1];
    const float* W  = (const float*)d_in[2];
    const float* b  = (const float*)d_in[3];
    float* out = (float*)d_out;

    int n = in_sizes[0] / IN_F;
    int E = in_sizes[1] / 2;
    const int* rowp = ei;       // edge_index[0] = source
    const int* colp = ei + E;   // edge_index[1] = target

    int nbins = (n + (1 << WBITS) - 1) >> WBITS;   // 196 for n=100000 (<= MAXBINS)

    // workspace layout (no aliasing: ebuf live concurrently with h writes)
    char* wp = (char*)d_ws;
    ushort_t* h    = (ushort_t*)wp;                   // n*64 bf16 = 12.8 MB
    unsigned* ebuf = (unsigned*)(wp + (size_t)n * OUT_F * 2);   // E uint32 = 6.4 MB
    int* bucket    = (int*)(ebuf + E);                // E int = 6.4 MB
    ushort_t* wfrag = (ushort_t*)(bucket + E);        // 32 KB (16B-aligned)
    int* start     = (int*)(wfrag + 16384);           // (n+1) int
    float* dinv    = (float*)(start + n + 1);         // n f32
    int* binCnt    = (int*)(dinv + n);                // MAXBINS int
    int* binStart  = binCnt + MAXBINS;                // MAXBINS+1 int
    int* binCursor = binStart + MAXBINS + 1;          // MAXBINS int
    int* partialCnt= binCursor + MAXBINS;             // SCAT_BLOCKS*MAXBINS int = 512 KB

    int gemmBlocks = (n + 63) / 64;

    hipMemsetAsync(binCnt, 0, MAXBINS * sizeof(int), stream);
    init_kernel<<<SCAT_BLOCKS, 256, 0, stream>>>(W, wfrag, colp, binCnt, partialCnt, E, nbins);
    bin_scan_kernel<<<1, MAXBINS, 0, stream>>>(binCnt, binStart, binCursor, start + n, nbins);
    mega_kernel<<<gemmBlocks + SCAT_BLOCKS, 256, 0, stream>>>(x, wfrag, h, rowp, colp,
                                                              partialCnt, binCursor, ebuf,
                                                              n, E, nbins, gemmBlocks);
    fine_build_kernel<<<nbins, 512, 0, stream>>>(ebuf, binStart, start, dinv, bucket, n);
    gather_kernel<<<(n + 3) / 4, 256, 0, stream>>>(start, bucket, h, dinv, b, out, n);
}

// Round 17
// 127.336 us; speedup vs baseline: 6.0408x; 1.0515x over previous
//
#include <hip/hip_runtime.h>

// GCNConv: out = D^-1/2 (A + I) D^-1/2 (x W) + b
// x: [N,256] f32, edge_index: [2,E] int, W: [256,64] f32, b: [64] f32
// out: [N,64] f32
//
// init (wfrag + per-chunk bin counts + global hist) -> bin_scan ->
// mega (GEMM blocks first; scatter blocks LDS-bucket-sort their chunk and
// flush coalesced) -> fine_build (CSR, 512-node bins) -> gather (8-subgroup uint4).

#define IN_F 256
#define OUT_F 64
#define WBITS 9                  // fine window = 512 nodes per coarse bin
#define MAXBINS 256
#define CSHIFT 23                // packed: row | (col_local << 23)
#define ROWMASK 0x7FFFFFu        // n < 2^23
#define CHUNK 4096               // edges per scatter block (LDS-sortable)

typedef unsigned short ushort_t;
typedef short bf16x8 __attribute__((ext_vector_type(8)));
typedef float f32x4 __attribute__((ext_vector_type(4)));

static __device__ __forceinline__ unsigned f2bf1(float f) {
    unsigned u = __float_as_uint(f);
    return (u + 0x7FFFu + ((u >> 16) & 1u)) >> 16;   // RNE
}
static __device__ __forceinline__ unsigned pk2(float a, float b) {
    return f2bf1(a) | (f2bf1(b) << 16);
}
static __device__ __forceinline__ ushort_t f2bf(float f) { return (ushort_t)f2bf1(f); }
static __device__ __forceinline__ float bf2f(ushort_t h) {
    return __uint_as_float(((unsigned)h) << 16);
}

// --- K1: wfrag pack (first 2048 threads) + per-chunk bin counts + global hist ---
__global__ __launch_bounds__(256) void init_kernel(const float* __restrict__ W,
                                                   ushort_t* __restrict__ wfrag,
                                                   const int* __restrict__ col,
                                                   int* __restrict__ binCnt,
                                                   int* __restrict__ partialCnt,
                                                   int E, int nbins) {
    int gt = blockIdx.x * 256 + threadIdx.x;
    if (gt < 2048) {   // W fragment pack: slot t=(kk*4+ct)*64+l
        int t = gt;
        int kk = t >> 8;
        int ct = (t >> 6) & 3;
        int l  = t & 63;
        int k0 = kk * 32 + (l >> 4) * 8;
        int c  = ct * 16 + (l & 15);
        unsigned u0 = pk2(W[(k0 + 0) * OUT_F + c], W[(k0 + 1) * OUT_F + c]);
        unsigned u1 = pk2(W[(k0 + 2) * OUT_F + c], W[(k0 + 3) * OUT_F + c]);
        unsigned u2 = pk2(W[(k0 + 4) * OUT_F + c], W[(k0 + 5) * OUT_F + c]);
        unsigned u3 = pk2(W[(k0 + 6) * OUT_F + c], W[(k0 + 7) * OUT_F + c]);
        ((uint4*)wfrag)[t] = make_uint4(u0, u1, u2, u3);
    }
    __shared__ int hist[MAXBINS];
    int tid = threadIdx.x;
    if (tid < nbins) hist[tid] = 0;
    __syncthreads();
    int s = blockIdx.x * CHUNK;
    int epos = min(E, s + CHUNK);
    for (int e = s + tid; e < epos; e += 256)
        atomicAdd(&hist[col[e] >> WBITS], 1);
    __syncthreads();
    if (tid < nbins) {
        int c = hist[tid];
        partialCnt[blockIdx.x * MAXBINS + tid] = c;
        if (c) atomicAdd(&binCnt[tid], c);
    }
}

// --- K2: exclusive scan of binCnt -> binStart, binCursor; start[n] = E ---
__global__ void bin_scan_kernel(const int* __restrict__ binCnt, int* __restrict__ binStart,
                                int* __restrict__ binCursor, int* __restrict__ start_n,
                                int nbins) {
    __shared__ int lds[MAXBINS];
    int tid = threadIdx.x;   // MAXBINS threads
    int v = (tid < nbins) ? binCnt[tid] : 0;
    lds[tid] = v;
    __syncthreads();
    for (int d = 1; d < MAXBINS; d <<= 1) {
        int t = (tid >= d) ? lds[tid - d] : 0;
        __syncthreads();
        lds[tid] += t;
        __syncthreads();
    }
    if (tid < nbins) {
        int ex = lds[tid] - v;
        binStart[tid] = ex;
        binCursor[tid] = ex;
    }
    if (tid == MAXBINS - 1) {
        binStart[nbins] = lds[MAXBINS - 1];   // = E
        start_n[0] = lds[MAXBINS - 1];        // start[n] = E
    }
}

// --- K3 MEGA: blocks [0,gemmBlocks) = MFMA GEMM h=xW (bf16, unscaled);
//              blocks [gemmBlocks, +SB) = LDS-bucket-sorted coalesced scatter ---
__global__ __launch_bounds__(256) void mega_kernel(const float* __restrict__ x,
                                                   const ushort_t* __restrict__ wfrag,
                                                   ushort_t* __restrict__ h,
                                                   const int* __restrict__ row,
                                                   const int* __restrict__ col,
                                                   const int* __restrict__ partialCnt,
                                                   int* __restrict__ binCursor,
                                                   unsigned* __restrict__ ebuf,
                                                   int n, int E, int nbins, int gemmBlocks) {
    int tid = threadIdx.x;

    if (blockIdx.x < gemmBlocks) {
        // ---------------- GEMM path ----------------
        int l  = tid & 63;
        int lr = l & 15;
        int lg = l >> 4;
        int rowbase = blockIdx.x * 64 + (tid >> 6) * 16;
        int arow = rowbase + lr;
        int lrow = (arow < n) ? arow : (n - 1);
        const float* xp = x + (size_t)lrow * IN_F + lg * 8;
        const uint4* wf = (const uint4*)wfrag;

        f32x4 acc0 = {0.f, 0.f, 0.f, 0.f};
        f32x4 acc1 = {0.f, 0.f, 0.f, 0.f};
        f32x4 acc2 = {0.f, 0.f, 0.f, 0.f};
        f32x4 acc3 = {0.f, 0.f, 0.f, 0.f};

        #pragma unroll
        for (int kk = 0; kk < 8; ++kk) {
            float4 xa = *(const float4*)(xp + kk * 32);
            float4 xb = *(const float4*)(xp + kk * 32 + 4);
            union { bf16x8 v; unsigned u[4]; } A;
            A.u[0] = pk2(xa.x, xa.y);
            A.u[1] = pk2(xa.z, xa.w);
            A.u[2] = pk2(xb.x, xb.y);
            A.u[3] = pk2(xb.z, xb.w);
            union { uint4 q; bf16x8 v; } B0, B1, B2, B3;
            B0.q = wf[(kk * 4 + 0) * 64 + l];
            B1.q = wf[(kk * 4 + 1) * 64 + l];
            B2.q = wf[(kk * 4 + 2) * 64 + l];
            B3.q = wf[(kk * 4 + 3) * 64 + l];
            acc0 = __builtin_amdgcn_mfma_f32_16x16x32_bf16(A.v, B0.v, acc0, 0, 0, 0);
            acc1 = __builtin_amdgcn_mfma_f32_16x16x32_bf16(A.v, B1.v, acc1, 0, 0, 0);
            acc2 = __builtin_amdgcn_mfma_f32_16x16x32_bf16(A.v, B2.v, acc2, 0, 0, 0);
            acc3 = __builtin_amdgcn_mfma_f32_16x16x32_bf16(A.v, B3.v, acc3, 0, 0, 0);
        }

        #pragma unroll
        for (int q = 0; q < 4; ++q) {
            int r = rowbase + lg * 4 + q;
            if (r < n) {
                ushort_t* gp = h + (size_t)r * OUT_F + lr;
                gp[0]  = f2bf(acc0[q]);
                gp[16] = f2bf(acc1[q]);
                gp[32] = f2bf(acc2[q]);
                gp[48] = f2bf(acc3[q]);
            }
        }
    } else {
        // ---------- LDS-bucket-sorted scatter (coalesced flush) ----------
        __shared__ int gbase[MAXBINS];       // global base of this block's run per bin
        __shared__ int lbase[MAXBINS];       // local exclusive scan of counts
        __shared__ int lcur[MAXBINS];        // local placement cursor
        __shared__ unsigned sorted[CHUNK];   // bin-sorted packed edges (16 KB)
        __shared__ int sdst[CHUNK];          // global dest index per slot (16 KB)

        int sb = blockIdx.x - gemmBlocks;
        int s = sb * CHUNK;
        int epos = min(E, s + CHUNK);

        // 1) claim global space per bin; 2) local exclusive scan (Hillis-Steele)
        int c = (tid < nbins) ? partialCnt[sb * MAXBINS + tid] : 0;
        if (tid < nbins) gbase[tid] = c ? atomicAdd(&binCursor[tid], c) : 0;
        lbase[tid] = c;
        __syncthreads();
        for (int d = 1; d < MAXBINS; d <<= 1) {
            int t = (tid >= d) ? lbase[tid - d] : 0;
            __syncthreads();
            lbase[tid] += t;
            __syncthreads();
        }
        int ex = lbase[tid] - c;
        lbase[tid] = ex;
        lcur[tid] = ex;
        __syncthreads();

        // 3) place edges into sorted LDS slots, record global dest
        for (int e = s + tid; e < epos; e += 256) {
            int cc = col[e];
            int bin = cc >> WBITS;
            int slot = atomicAdd(&lcur[bin], 1);
            sorted[slot] = (unsigned)row[e] | ((unsigned)(cc & ((1 << WBITS) - 1)) << CSHIFT);
            sdst[slot]   = gbase[bin] + (slot - lbase[bin]);
        }
        __syncthreads();

        // 4) coalesced flush: consecutive slots -> consecutive global addresses
        int csize = epos - s;
        for (int i = tid; i < csize; i += 256)
            ebuf[sdst[i]] = sorted[i];
    }
}

// --- K4: per-bin fine CSR build (deg/dinv/start/bucket), 512-node bins ---
__global__ __launch_bounds__(512) void fine_build_kernel(const unsigned* __restrict__ ebuf,
                                                         const int* __restrict__ binStart,
                                                         int* __restrict__ start,
                                                         float* __restrict__ dinv,
                                                         int* __restrict__ bucket, int n) {
    __shared__ int sdeg[512];
    __shared__ int scur[512];
    int b = blockIdx.x;
    int lo = b << WBITS;
    int wcnt = min(512, n - lo);
    int tid = threadIdx.x;
    sdeg[tid] = 0;
    __syncthreads();
    int s = binStart[b], epos = binStart[b + 1];
    for (int e = s + tid; e < epos; e += 512)
        atomicAdd(&sdeg[ebuf[e] >> CSHIFT], 1);
    __syncthreads();
    int d = sdeg[tid];
    if (tid < wcnt) dinv[lo + tid] = rsqrtf((float)(d + 1));
    for (int dd = 1; dd < 512; dd <<= 1) {
        int t = (tid >= dd) ? sdeg[tid - dd] : 0;
        __syncthreads();
        sdeg[tid] += t;
        __syncthreads();
    }
    int ex = sdeg[tid] - d;
    if (tid < wcnt) start[lo + tid] = s + ex;
    scur[tid] = ex;
    __syncthreads();
    for (int e = s + tid; e < epos; e += 512) {
        unsigned pr = ebuf[e];
        int pos = atomicAdd(&scur[pr >> CSHIFT], 1);
        bucket[s + pos] = (int)(pr & ROWMASK);
    }
}

// --- K5: out[c] = dinv[c] * (sum_j h[src_j]*dinv[src_j] + h[c]*dinv[c]) + b ---
// Wave = 1 node; 8 subgroups of 8 lanes walk different edges; lane holds
// 8 features (16 B uint4). One VMEM issue = 8 edge-rows; unroll-2 => 16 in flight.
__global__ __launch_bounds__(256) void gather_kernel(const int* __restrict__ start,
                              const int* __restrict__ bucket, const ushort_t* __restrict__ h,
                              const float* __restrict__ dinv, const float* __restrict__ b,
                              float* __restrict__ out, int n) {
    int lane = threadIdx.x & 63;
    int node = blockIdx.x * 4 + (threadIdx.x >> 6);
    if (node >= n) return;
    int f8  = lane & 7;         // features 8*f8 .. 8*f8+7
    int grp = lane >> 3;        // edge subgroup 0..7
    int s0  = start[node];
    int cnt = start[node + 1] - s0;
    const int* bp = bucket + s0;
    int last = cnt - 1;

    float a0 = 0.f, a1 = 0.f, a2 = 0.f, a3 = 0.f;
    float a4 = 0.f, a5 = 0.f, a6 = 0.f, a7 = 0.f;
    union { uint4 q; ushort_t s[8]; } VA, VB;
    for (int e0 = 0; e0 < cnt; e0 += 16) {
        int eA = e0 + grp;
        int eB = e0 + 8 + grp;
        int iA = bp[min(eA, last)];
        int iB = bp[min(eB, last)];
        VA.q = *(const uint4*)(h + (size_t)iA * OUT_F + f8 * 8);
        VB.q = *(const uint4*)(h + (size_t)iB * OUT_F + f8 * 8);
        float dA = (eA < cnt) ? dinv[iA] : 0.f;
        float dB = (eB < cnt) ? dinv[iB] : 0.f;
        a0 += bf2f(VA.s[0]) * dA;
        a1 += bf2f(VA.s[1]) * dA;
        a2 += bf2f(VA.s[2]) * dA;
        a3 += bf2f(VA.s[3]) * dA;
        a4 += bf2f(VA.s[4]) * dA;
        a5 += bf2f(VA.s[5]) * dA;
        a6 += bf2f(VA.s[6]) * dA;
        a7 += bf2f(VA.s[7]) * dA;
        a0 += bf2f(VB.s[0]) * dB;
        a1 += bf2f(VB.s[1]) * dB;
        a2 += bf2f(VB.s[2]) * dB;
        a3 += bf2f(VB.s[3]) * dB;
        a4 += bf2f(VB.s[4]) * dB;
        a5 += bf2f(VB.s[5]) * dB;
        a6 += bf2f(VB.s[6]) * dB;
        a7 += bf2f(VB.s[7]) * dB;
    }
    // cross-subgroup reduce: lanes f8, f8+8, ..., f8+56 hold the same features
    #pragma unroll
    for (int off = 8; off < 64; off <<= 1) {
        a0 += __shfl_xor(a0, off, 64);
        a1 += __shfl_xor(a1, off, 64);
        a2 += __shfl_xor(a2, off, 64);
        a3 += __shfl_xor(a3, off, 64);
        a4 += __shfl_xor(a4, off, 64);
        a5 += __shfl_xor(a5, off, 64);
        a6 += __shfl_xor(a6, off, 64);
        a7 += __shfl_xor(a7, off, 64);
    }

    if (grp == 0) {
        union { uint4 q; ushort_t s[8]; } SV;
        SV.q = *(const uint4*)(h + (size_t)node * OUT_F + f8 * 8);
        float dc = dinv[node];
        const float4* bv = (const float4*)b;
        float4 o0, o1;
        o0.x = (a0 + bf2f(SV.s[0]) * dc) * dc + bv[f8 * 2].x;
        o0.y = (a1 + bf2f(SV.s[1]) * dc) * dc + bv[f8 * 2].y;
        o0.z = (a2 + bf2f(SV.s[2]) * dc) * dc + bv[f8 * 2].z;
        o0.w = (a3 + bf2f(SV.s[3]) * dc) * dc + bv[f8 * 2].w;
        o1.x = (a4 + bf2f(SV.s[4]) * dc) * dc + bv[f8 * 2 + 1].x;
        o1.y = (a5 + bf2f(SV.s[5]) * dc) * dc + bv[f8 * 2 + 1].y;
        o1.z = (a6 + bf2f(SV.s[6]) * dc) * dc + bv[f8 * 2 + 1].z;
        o1.w = (a7 + bf2f(SV.s[7]) * dc) * dc + bv[f8 * 2 + 1].w;
        float4* op = (float4*)(out + (size_t)node * OUT_F + f8 * 8);
        op[0] = o0;
        op[1] = o1;
    }
}

extern "C" void kernel_launch(void* const* d_in, const int* in_sizes, int n_in,
                              void* d_out, int out_size, void* d_ws, size_t ws_size,
                              hipStream_t stream) {
    const float* x  = (const float*)d_in[0];
    const int*   ei = (const int*)d_in[1];
    const float* W  = (const float*)d_in[2];
    const float* b  = (const float*)d_in[3];
    float* out = (float*)d_out;

    int n = in_sizes[0] / IN_F;
    int E = in_sizes[1] / 2;
    const int* rowp = ei;       // edge_index[0] = source
    const int* colp = ei + E;   // edge_index[1] = target

    int nbins = (n + (1 << WBITS) - 1) >> WBITS;   // 196 for n=100000 (<= MAXBINS)
    int SB = (E + CHUNK - 1) / CHUNK;              // 391 scatter blocks for E=1.6M

    // workspace layout (no aliasing: ebuf live concurrently with h writes)
    char* wp = (char*)d_ws;
    ushort_t* h    = (ushort_t*)wp;                   // n*64 bf16 = 12.8 MB
    unsigned* ebuf = (unsigned*)(wp + (size_t)n * OUT_F * 2);   // E uint32 = 6.4 MB
    int* bucket    = (int*)(ebuf + E);                // E int = 6.4 MB
    ushort_t* wfrag = (ushort_t*)(bucket + E);        // 32 KB (16B-aligned)
    int* start     = (int*)(wfrag + 16384);           // (n+1) int
    float* dinv    = (float*)(start + n + 1);         // n f32
    int* binCnt    = (int*)(dinv + n);                // MAXBINS int
    int* binStart  = binCnt + MAXBINS;                // MAXBINS+1 int
    int* binCursor = binStart + MAXBINS + 1;          // MAXBINS int
    int* partialCnt= binCursor + MAXBINS;             // SB*MAXBINS int (<=512 rows)

    int gemmBlocks = (n + 63) / 64;

    hipMemsetAsync(binCnt, 0, MAXBINS * sizeof(int), stream);
    init_kernel<<<SB, 256, 0, stream>>>(W, wfrag, colp, binCnt, partialCnt, E, nbins);
    bin_scan_kernel<<<1, MAXBINS, 0, stream>>>(binCnt, binStart, binCursor, start + n, nbins);
    mega_kernel<<<gemmBlocks + SB, 256, 0, stream>>>(x, wfrag, h, rowp, colp,
                                                     partialCnt, binCursor, ebuf,
                                                     n, E, nbins, gemmBlocks);
    fine_build_kernel<<<nbins, 512, 0, stream>>>(ebuf, binStart, start, dinv, bucket, n);
    gather_kernel<<<(n + 3) / 4, 256, 0, stream>>>(start, bucket, h, dinv, b, out, n);
}